// Round 1
// baseline (643.493 us; speedup 1.0000x reference)
//
#include <hip/hip_runtime.h>
#include <math.h>

#define BB 4
#define NN 2048
#define EE 2048

typedef __attribute__((ext_vector_type(8))) unsigned short ushort8;
typedef __attribute__((ext_vector_type(4))) float f32x4;

// ---------- helpers ----------
__device__ __forceinline__ unsigned short f2bf(float f) {
  unsigned int u = __float_as_uint(f);
  u = u + 0x7fffu + ((u >> 16) & 1u);   // RNE; inputs are finite
  return (unsigned short)(u >> 16);
}

__device__ __forceinline__ f32x4 mfma16(ushort8 a, ushort8 b, f32x4 c) {
  asm("v_mfma_f32_16x16x32_bf16 %0, %1, %2, %0" : "+v"(c) : "v"(a), "v"(b));
  return c;
}

__device__ __forceinline__ void gload16(const void* g, void* l) {
  __builtin_amdgcn_global_load_lds(
      (__attribute__((address_space(1))) void*)g,
      (__attribute__((address_space(3))) void*)l, 16, 0, 0);
}

// ---------- fp32 -> bf16 conversion (vectorized) ----------
__global__ __launch_bounds__(256) void k_f32_to_bf16(const float* __restrict__ in,
                                                     unsigned short* __restrict__ out) {
  size_t i = (size_t)blockIdx.x * 256 + threadIdx.x;   // 8 elems each
  const float4* ip = (const float4*)in;
  float4 a = ip[i * 2];
  float4 b = ip[i * 2 + 1];
  ushort8 o;
  o[0] = f2bf(a.x); o[1] = f2bf(a.y); o[2] = f2bf(a.z); o[3] = f2bf(a.w);
  o[4] = f2bf(b.x); o[5] = f2bf(b.y); o[6] = f2bf(b.z); o[7] = f2bf(b.w);
  *((ushort8*)out + i) = o;
}

// ---------- bf16 transpose [N,E] -> [E,N] per batch ----------
__global__ __launch_bounds__(256) void k_transpose(const unsigned short* __restrict__ in,
                                                   unsigned short* __restrict__ out) {
  __shared__ __attribute__((aligned(16))) unsigned short tile[64][72]; // 144B stride, 16B-aligned rows
  const long z = blockIdx.z;
  const long eb = (long)blockIdx.x * 64;
  const long nb = (long)blockIdx.y * 64;
  const unsigned short* ip = in + z * (long)NN * EE;
  unsigned short* op = out + z * (long)NN * EE;
  const int t = threadIdx.x;
  const int r = t >> 3;          // 0..31
  const int c = (t & 7) * 8;     // 0..56

  ushort8 u0 = *(const ushort8*)(ip + (nb + r) * EE + eb + c);
  ushort8 u1 = *(const ushort8*)(ip + (nb + 32 + r) * EE + eb + c);
  *(ushort8*)&tile[r][c] = u0;
  *(ushort8*)&tile[r + 32][c] = u1;
  __syncthreads();
  ushort8 o0, o1;
#pragma unroll
  for (int j = 0; j < 8; j++) { o0[j] = tile[c + j][r]; o1[j] = tile[c + j][r + 32]; }
  *(ushort8*)(op + (eb + r) * NN + nb + c) = o0;
  *(ushort8*)(op + (eb + r + 32) * NN + nb + c) = o1;
}

// ---------- GEMM: C[m,n] = sum_k A[m,k]*B[n,k]  (both row-major, B^T form) ----------
// EPI 0: bf16 out (+bias if non-null)   EPI 1: f32 out, acc*scale + mask*(-1e9)
// EPI 2: f32 out + bias
template <int EPI>
__global__ __launch_bounds__(256) void k_gemm_bt(
    const unsigned short* __restrict__ A, long lda, long sA,
    const unsigned short* __restrict__ Bm, long ldb, long sB,
    void* __restrict__ Cv, long ldc, long sC, int K,
    const float* __restrict__ bias,
    const int* __restrict__ mask, long sMask, float scale) {
  __shared__ __attribute__((aligned(16))) unsigned short As[128 * 32];
  __shared__ __attribute__((aligned(16))) unsigned short Bs[128 * 32];
  const int t = threadIdx.x;
  const int lane = t & 63;
  const int w = t >> 6;
  const int wr = (w >> 1) * 64;
  const int wc = (w & 1) * 64;
  const long z = blockIdx.z;
  const long m0 = (long)blockIdx.y * 128;
  const long n0 = (long)blockIdx.x * 128;
  const unsigned short* Ab = A + z * sA;
  const unsigned short* Bb = Bm + z * sB;

  const int sr = t >> 2;          // 0..63
  const int sc = (t & 3) * 8;     // 0,8,16,24
  const unsigned short* ga0 = Ab + (m0 + sr) * lda + sc;
  const unsigned short* ga1 = ga0 + 64 * lda;
  const unsigned short* gb0 = Bb + (n0 + sr) * ldb + sc;
  const unsigned short* gb1 = gb0 + 64 * ldb;
  unsigned short* la0 = As + sr * 32 + sc;   // LDS byte off == t*16 within wave-linear order
  unsigned short* la1 = la0 + 64 * 32;
  unsigned short* lb0 = Bs + sr * 32 + sc;
  unsigned short* lb1 = lb0 + 64 * 32;

  f32x4 acc[4][4] = {};

  const int arow = wr + (lane & 15);
  const int brow = wc + (lane & 15);
  const int kof = (lane >> 4) * 8;

  for (int kt = 0; kt < K; kt += 32) {
    gload16(ga0, la0); gload16(ga1, la1);
    gload16(gb0, lb0); gload16(gb1, lb1);
    ga0 += 32; ga1 += 32; gb0 += 32; gb1 += 32;
    __syncthreads();
    ushort8 af[4], bfr[4];
#pragma unroll
    for (int mi = 0; mi < 4; mi++)
      af[mi] = *(const ushort8*)(As + (arow + mi * 16) * 32 + kof);
#pragma unroll
    for (int ni = 0; ni < 4; ni++)
      bfr[ni] = *(const ushort8*)(Bs + (brow + ni * 16) * 32 + kof);
#pragma unroll
    for (int mi = 0; mi < 4; mi++)
#pragma unroll
      for (int ni = 0; ni < 4; ni++)
        acc[mi][ni] = mfma16(af[mi], bfr[ni], acc[mi][ni]);
    __syncthreads();
  }

  const int crow = wr + ((lane >> 4) << 2);  // + mi*16 + r
  const int ccol = wc + (lane & 15);         // + ni*16

  if (EPI == 0) {
    unsigned short* Co = (unsigned short*)Cv + z * sC;
#pragma unroll
    for (int mi = 0; mi < 4; mi++)
#pragma unroll
      for (int r = 0; r < 4; r++) {
        long row = m0 + crow + mi * 16 + r;
#pragma unroll
        for (int ni = 0; ni < 4; ni++) {
          long col = n0 + ccol + ni * 16;
          float v = acc[mi][ni][r];
          if (bias) v += bias[col];
          Co[row * ldc + col] = f2bf(v);
        }
      }
  } else if (EPI == 1) {
    float* Co = (float*)Cv + z * sC;
    const int* Mp = mask + z * sMask;
#pragma unroll
    for (int mi = 0; mi < 4; mi++)
#pragma unroll
      for (int r = 0; r < 4; r++) {
        long row = m0 + crow + mi * 16 + r;
#pragma unroll
        for (int ni = 0; ni < 4; ni++) {
          long col = n0 + ccol + ni * 16;
          float v = acc[mi][ni][r] * scale + (float)Mp[row * ldc + col] * -1e9f;
          Co[row * ldc + col] = v;
        }
      }
  } else {
    float* Co = (float*)Cv + z * sC;
#pragma unroll
    for (int mi = 0; mi < 4; mi++)
#pragma unroll
      for (int r = 0; r < 4; r++) {
        long row = m0 + crow + mi * 16 + r;
#pragma unroll
        for (int ni = 0; ni < 4; ni++) {
          long col = n0 + ccol + ni * 16;
          Co[row * ldc + col] = acc[mi][ni][r] + bias[col];
        }
      }
  }
}

// ---------- edge gate + softmax, one row per block; writes bf16 attn in place ----------
__global__ __launch_bounds__(256) void k_edge_softmax(float* __restrict__ scores,
                                                      const float* __restrict__ We,
                                                      const float* __restrict__ be) {
  __shared__ float r1[4], r2[4], r3[4];
  const long row = blockIdx.x;
  float* srow = scores + row * (long)NN;
  const int t = threadIdx.x;
  const int lane = t & 63;
  const int w = t >> 6;

  float4 a = *(const float4*)(srow + t * 8);
  float4 b = *(const float4*)(srow + t * 8 + 4);
  float s[8] = {a.x, a.y, a.z, a.w, b.x, b.y, b.z, b.w};
  float4 wa = *(const float4*)(We + t * 8);
  float4 wb = *(const float4*)(We + t * 8 + 4);
  float wv[8] = {wa.x, wa.y, wa.z, wa.w, wb.x, wb.y, wb.z, wb.w};

  float dot = 0.f;
#pragma unroll
  for (int j = 0; j < 8; j++) dot += s[j] * wv[j];
#pragma unroll
  for (int off = 32; off >= 1; off >>= 1) dot += __shfl_down(dot, off);
  if (lane == 0) r1[w] = dot;
  __syncthreads();
  float edot = r1[0] + r1[1] + r1[2] + r1[3] + be[0];
  float edge = 1.0f / (1.0f + expf(-edot));

  float mx = -3.4e38f;
#pragma unroll
  for (int j = 0; j < 8; j++) { s[j] *= edge; mx = fmaxf(mx, s[j]); }
#pragma unroll
  for (int off = 32; off >= 1; off >>= 1) mx = fmaxf(mx, __shfl_down(mx, off));
  if (lane == 0) r2[w] = mx;
  __syncthreads();
  mx = fmaxf(fmaxf(r2[0], r2[1]), fmaxf(r2[2], r2[3]));

  float sum = 0.f;
  float p[8];
#pragma unroll
  for (int j = 0; j < 8; j++) { p[j] = expf(s[j] - mx); sum += p[j]; }
#pragma unroll
  for (int off = 32; off >= 1; off >>= 1) sum += __shfl_down(sum, off);
  if (lane == 0) r3[w] = sum;
  __syncthreads();
  sum = r3[0] + r3[1] + r3[2] + r3[3];
  float inv = 1.0f / sum;

  ushort8 o;
#pragma unroll
  for (int j = 0; j < 8; j++) o[j] = f2bf(p[j] * inv);
  *(ushort8*)((unsigned short*)srow + t * 8) = o;   // in-place: all reads done before syncs
}

// ---------- launch ----------
extern "C" void kernel_launch(void* const* d_in, const int* in_sizes, int n_in,
                              void* d_out, int out_size, void* d_ws, size_t ws_size,
                              hipStream_t stream) {
  (void)in_sizes; (void)n_in; (void)out_size; (void)ws_size;
  const float* query = (const float*)d_in[0];
  const float* key_  = (const float*)d_in[1];
  const float* value = (const float*)d_in[2];
  const int*   mask  = (const int*)d_in[3];
  const float* Wq = (const float*)d_in[4];
  const float* bq = (const float*)d_in[5];
  const float* Wk = (const float*)d_in[6];
  const float* bk = (const float*)d_in[7];
  const float* Wv = (const float*)d_in[8];
  const float* bv = (const float*)d_in[9];
  const float* We = (const float*)d_in[10];
  const float* be = (const float*)d_in[11];
  const float* Wo = (const float*)d_in[12];
  const float* bo = (const float*)d_in[13];
  float* out = (float*)d_out;

  const long NE = (long)BB * NN * EE;        // 16,777,216 elements
  const size_t SZ = (size_t)NE * 2;          // 33,554,432 bytes
  char* ws = (char*)d_ws;
  unsigned short* X  = (unsigned short*)(ws);           // conv buffer, later Vt
  unsigned short* Qb = (unsigned short*)(ws + SZ);
  unsigned short* Kb = (unsigned short*)(ws + 2 * SZ);
  unsigned short* Vb = (unsigned short*)(ws + 3 * SZ);  // later O
  unsigned short* Wb = (unsigned short*)(ws + 4 * SZ);  // 4 x E*E bf16
  float* SC = (float*)(ws + 5 * SZ);                    // scores fp32 (2*SZ bytes); attn bf16 in place

  const float scale = 1.0f / sqrtf((float)EE);
  dim3 blk(256);
  const long WE2 = (long)EE * EE;

  // weights -> bf16
  k_f32_to_bf16<<<2048, blk, 0, stream>>>(Wq, Wb + 0 * WE2);
  k_f32_to_bf16<<<2048, blk, 0, stream>>>(Wk, Wb + 1 * WE2);
  k_f32_to_bf16<<<2048, blk, 0, stream>>>(Wv, Wb + 2 * WE2);
  k_f32_to_bf16<<<2048, blk, 0, stream>>>(Wo, Wb + 3 * WE2);

  // projections (M = B*N = 8192)
  k_f32_to_bf16<<<8192, blk, 0, stream>>>(query, X);
  k_gemm_bt<0><<<dim3(16, 64, 1), blk, 0, stream>>>(X, EE, 0, Wb + 0 * WE2, EE, 0,
      Qb, EE, 0, EE, bq, nullptr, 0, 0.f);
  k_f32_to_bf16<<<8192, blk, 0, stream>>>(key_, X);
  k_gemm_bt<0><<<dim3(16, 64, 1), blk, 0, stream>>>(X, EE, 0, Wb + 1 * WE2, EE, 0,
      Kb, EE, 0, EE, bk, nullptr, 0, 0.f);
  k_f32_to_bf16<<<8192, blk, 0, stream>>>(value, X);
  k_gemm_bt<0><<<dim3(16, 64, 1), blk, 0, stream>>>(X, EE, 0, Wb + 2 * WE2, EE, 0,
      Vb, EE, 0, EE, bv, nullptr, 0, 0.f);

  // Vt[e,n] = V[n,e]  (into X; conv buffer dead now)
  k_transpose<<<dim3(32, 32, BB), blk, 0, stream>>>(Vb, X);

  // scores = Q K^T * scale + mask*(-1e9)   [fp32]
  k_gemm_bt<1><<<dim3(16, 16, BB), blk, 0, stream>>>(Qb, EE, (long)NN * EE, Kb, EE, (long)NN * EE,
      SC, NN, (long)NN * NN, EE, nullptr, mask, (long)NN * NN, scale);

  // edge gate + softmax -> bf16 attn in place (row stride 2N bf16 elements)
  k_edge_softmax<<<BB * NN, blk, 0, stream>>>(SC, We, be);

  // O = attn * Vt^T  -> Vb region (bf16)
  k_gemm_bt<0><<<dim3(16, 16, BB), blk, 0, stream>>>((const unsigned short*)SC, 2 * NN,
      (long)NN * 2 * NN, X, NN, (long)EE * NN, Vb, EE, (long)NN * EE, NN,
      nullptr, nullptr, 0, 0.f);

  // out = O * Wo^T + bo   [fp32]
  k_gemm_bt<2><<<dim3(16, 64, 1), blk, 0, stream>>>(Vb, EE, 0, Wb + 3 * WE2, EE, 0,
      out, EE, 0, EE, bo, nullptr, 0, 0.f);
}

// Round 2
// 604.007 us; speedup vs baseline: 1.0654x; 1.0654x over previous
//
#include <hip/hip_runtime.h>
#include <math.h>

#define BB 4
#define NN 2048
#define EE 2048

typedef __attribute__((ext_vector_type(8))) unsigned short ushort8;
typedef __attribute__((ext_vector_type(4))) float f32x4;

// ---------- helpers ----------
__device__ __forceinline__ unsigned short f2bf(float f) {
  unsigned int u = __float_as_uint(f);
  u = u + 0x7fffu + ((u >> 16) & 1u);   // RNE; inputs are finite
  return (unsigned short)(u >> 16);
}

__device__ __forceinline__ f32x4 mfma16(ushort8 a, ushort8 b, f32x4 c) {
  asm("v_mfma_f32_16x16x32_bf16 %0, %1, %2, %0" : "+v"(c) : "v"(a), "v"(b));
  return c;
}

__device__ __forceinline__ void gload16(const void* g, void* l) {
  __builtin_amdgcn_global_load_lds(
      (__attribute__((address_space(1))) void*)g,
      (__attribute__((address_space(3))) void*)l, 16, 0, 0);
}

#define BARRIER() do { asm volatile("" ::: "memory"); __builtin_amdgcn_s_barrier(); asm volatile("" ::: "memory"); } while (0)

// ---------- fp32 -> bf16 conversion (vectorized) ----------
__global__ __launch_bounds__(256) void k_f32_to_bf16(const float* __restrict__ in,
                                                     unsigned short* __restrict__ out) {
  size_t i = (size_t)blockIdx.x * 256 + threadIdx.x;   // 8 elems each
  const float4* ip = (const float4*)in;
  float4 a = ip[i * 2];
  float4 b = ip[i * 2 + 1];
  ushort8 o;
  o[0] = f2bf(a.x); o[1] = f2bf(a.y); o[2] = f2bf(a.z); o[3] = f2bf(a.w);
  o[4] = f2bf(b.x); o[5] = f2bf(b.y); o[6] = f2bf(b.z); o[7] = f2bf(b.w);
  *((ushort8*)out + i) = o;
}

// ---------- bf16 transpose [N,E] -> [E,N] per batch ----------
__global__ __launch_bounds__(256) void k_transpose(const unsigned short* __restrict__ in,
                                                   unsigned short* __restrict__ out) {
  __shared__ __attribute__((aligned(16))) unsigned short tile[64][72];
  const long z = blockIdx.z;
  const long eb = (long)blockIdx.x * 64;
  const long nb = (long)blockIdx.y * 64;
  const unsigned short* ip = in + z * (long)NN * EE;
  unsigned short* op = out + z * (long)NN * EE;
  const int t = threadIdx.x;
  const int r = t >> 3;
  const int c = (t & 7) * 8;

  ushort8 u0 = *(const ushort8*)(ip + (nb + r) * EE + eb + c);
  ushort8 u1 = *(const ushort8*)(ip + (nb + 32 + r) * EE + eb + c);
  *(ushort8*)&tile[r][c] = u0;
  *(ushort8*)&tile[r + 32][c] = u1;
  __syncthreads();
  ushort8 o0, o1;
#pragma unroll
  for (int j = 0; j < 8; j++) { o0[j] = tile[c + j][r]; o1[j] = tile[c + j][r + 32]; }
  *(ushort8*)(op + (eb + r) * NN + nb + c) = o0;
  *(ushort8*)(op + (eb + r + 32) * NN + nb + c) = o1;
}

// ---------- 256x256x64 8-wave 4-phase GEMM: C[m,n] = sum_k A[m,k]*B[n,k] ----------
// EPI 0: bf16 out (+bias if non-null)   EPI 1: f32, acc*scale + mask*(-1e9)   EPI 2: f32 + bias
// LDS: A,B double-buffered 256x64 bf16 tiles (128 KiB), st_16x32 XOR swizzle
// (phys byte ^= ((byte>>9)&1)<<5 within each 1024B 16x32 subtile); staging keeps
// LDS linear (global_load_lds) and pre-swizzles the GLOBAL source address.
template <int EPI>
__global__ __launch_bounds__(512, 2) void k_gemm256(
    const unsigned short* __restrict__ A, long lda, long sA,
    const unsigned short* __restrict__ Bm, long ldb, long sB,
    void* __restrict__ Cv, long ldc, long sC, int K,
    const float* __restrict__ bias,
    const int* __restrict__ mask, long sMask, float scale) {
  __shared__ __attribute__((aligned(16))) unsigned short As[2][16384];
  __shared__ __attribute__((aligned(16))) unsigned short Bs[2][16384];

  // bijective XCD-chunk swizzle (nwg is always a multiple of 8 here)
  const int gx = gridDim.x, gy = gridDim.y;
  int lin = (int)blockIdx.x + gx * ((int)blockIdx.y + gy * (int)blockIdx.z);
  int nwg = gx * gy * (int)gridDim.z;
  int chunk = nwg >> 3;
  int sw = (lin & 7) * chunk + (lin >> 3);
  int bz = sw / (gx * gy); int rem = sw - bz * (gx * gy);
  int by = rem / gx; int bx = rem - by * gx;

  const long m0 = (long)by * 256;
  const long n0 = (long)bx * 256;
  const unsigned short* Ab = A + (long)bz * sA;
  const unsigned short* Bb = Bm + (long)bz * sB;

  const int t = threadIdx.x;
  const int lane = t & 63;
  const int w = t >> 6;
  const int wm = w >> 2;          // 0..1 (M-warp)
  const int wn = w & 3;           // 0..3 (N-warp)

  // ---- staging: thread t's LDS linear dest byte p0=t*16 maps to logical q0 ----
  const int p0 = t * 16;
  const int q0 = p0 ^ (((p0 >> 9) & 1) << 5);
  const int srow = ((q0 >> 10) >> 1) * 16 + ((q0 >> 6) & 15);   // row in 128-row half
  const int scol = ((q0 >> 10) & 1) * 32 + ((q0 & 63) >> 1);    // col in 64-col K-step
  const unsigned short* Ga = Ab + (m0 + srow) * lda + scol;
  const unsigned short* Gb = Bb + (n0 + srow) * ldb + scol;
  const int ldst = t * 8;   // ushort index of round-0 dest

#define STAGE_A(buf, h, tile) do { \
    const unsigned short* g_ = Ga + (long)(tile) * 64 + (long)(h) * 128 * lda; \
    gload16(g_, &As[buf][(h) * 8192 + ldst]); \
    gload16(g_ + 64 * lda, &As[buf][(h) * 8192 + 4096 + ldst]); \
  } while (0)
#define STAGE_B(buf, h, tile) do { \
    const unsigned short* g_ = Gb + (long)(tile) * 64 + (long)(h) * 128 * ldb; \
    gload16(g_, &Bs[buf][(h) * 8192 + ldst]); \
    gload16(g_ + 64 * ldb, &Bs[buf][(h) * 8192 + 4096 + ldst]); \
  } while (0)

  // ---- read-side lane constants (swizzled ds_read addresses, ushort units) ----
  const int r = lane & 15;
  const int c2h = ((((lane >> 4) * 16) ^ (((lane >> 3) & 1) << 5)) >> 1);
  const int aoffL = wm * 8192 + r * 32 + c2h;                       // + mi*1024 + kk*512
  const int boffL = (wn >> 1) * 8192 + (wn & 1) * 4096 + r * 32 + c2h; // + ni*1024 + kk*512

  f32x4 acc[8][4] = {};
  ushort8 a[4][2], b[4][2];
  const int nt = K >> 6;

  // ---- prologue: tile0 (A h0,h1, B h0,h1) + tile1 (A h0,h1) => 12 loads ----
  STAGE_A(0, 0, 0); STAGE_A(0, 1, 0);
  STAGE_B(0, 0, 0); STAGE_B(0, 1, 0);
  STAGE_A(1, 0, 1); STAGE_A(1, 1, 1);
  asm volatile("s_waitcnt vmcnt(4)" ::: "memory");   // tile0 resident
  BARRIER();

  for (int kt = 0; kt < nt; ++kt) {
    const int c = kt & 1, nc = c ^ 1;
    const unsigned short* Ac = &As[c][0];
    const unsigned short* Bc = &Bs[c][0];

    // ---- P1: read A[mi0-3], B[ni0-1]; stage B(kt+1) h0; MFMA quad (0,0) ----
#pragma unroll
    for (int mi = 0; mi < 4; mi++)
#pragma unroll
      for (int kk = 0; kk < 2; kk++)
        a[mi][kk] = *(const ushort8*)(Ac + aoffL + mi * 1024 + kk * 512);
#pragma unroll
    for (int ni = 0; ni < 2; ni++)
#pragma unroll
      for (int kk = 0; kk < 2; kk++)
        b[ni][kk] = *(const ushort8*)(Bc + boffL + ni * 1024 + kk * 512);
    if (kt + 1 < nt) STAGE_B(nc, 0, kt + 1);
    BARRIER();
    __builtin_amdgcn_s_setprio(1);
#pragma unroll
    for (int mi = 0; mi < 4; mi++)
#pragma unroll
      for (int ni = 0; ni < 2; ni++)
#pragma unroll
        for (int kk = 0; kk < 2; kk++)
          acc[mi][ni] = mfma16(a[mi][kk], b[ni][kk], acc[mi][ni]);
    __builtin_amdgcn_s_setprio(0);
    BARRIER();

    // ---- P2: read B[ni2-3]; stage B(kt+1) h1; MFMA quad (0,1) ----
#pragma unroll
    for (int ni = 2; ni < 4; ni++)
#pragma unroll
      for (int kk = 0; kk < 2; kk++)
        b[ni][kk] = *(const ushort8*)(Bc + boffL + ni * 1024 + kk * 512);
    if (kt + 1 < nt) STAGE_B(nc, 1, kt + 1);
    BARRIER();
    __builtin_amdgcn_s_setprio(1);
#pragma unroll
    for (int mi = 0; mi < 4; mi++)
#pragma unroll
      for (int ni = 2; ni < 4; ni++)
#pragma unroll
        for (int kk = 0; kk < 2; kk++)
          acc[mi][ni] = mfma16(a[mi][kk], b[ni][kk], acc[mi][ni]);
    __builtin_amdgcn_s_setprio(0);
    BARRIER();

    // ---- P3: read A[mi4-7] (reuse regs); MFMA quad (1,0) ----
#pragma unroll
    for (int mi = 0; mi < 4; mi++)
#pragma unroll
      for (int kk = 0; kk < 2; kk++)
        a[mi][kk] = *(const ushort8*)(Ac + aoffL + (4 + mi) * 1024 + kk * 512);
    BARRIER();
    __builtin_amdgcn_s_setprio(1);
#pragma unroll
    for (int mi = 0; mi < 4; mi++)
#pragma unroll
      for (int ni = 0; ni < 2; ni++)
#pragma unroll
        for (int kk = 0; kk < 2; kk++)
          acc[4 + mi][ni] = mfma16(a[mi][kk], b[ni][kk], acc[4 + mi][ni]);
    __builtin_amdgcn_s_setprio(0);
    BARRIER();

    // ---- P4: stage A(kt+2) h0,h1 into buf c (its reads ended at P3); MFMA quad (1,1);
    //          counted vmcnt guarantees tile kt+1 resident before next iteration ----
    if (kt + 2 < nt) { STAGE_A(c, 0, kt + 2); STAGE_A(c, 1, kt + 2); }
    BARRIER();
    __builtin_amdgcn_s_setprio(1);
#pragma unroll
    for (int mi = 0; mi < 4; mi++)
#pragma unroll
      for (int ni = 2; ni < 4; ni++)
#pragma unroll
        for (int kk = 0; kk < 2; kk++)
          acc[4 + mi][ni] = mfma16(a[mi][kk], b[ni][kk], acc[4 + mi][ni]);
    __builtin_amdgcn_s_setprio(0);
    if (kt < nt - 2) { asm volatile("s_waitcnt vmcnt(4)" ::: "memory"); }
    else if (kt == nt - 2) { asm volatile("s_waitcnt vmcnt(0)" ::: "memory"); }
    BARRIER();
  }
#undef STAGE_A
#undef STAGE_B

  // ---- epilogue: C/D mapping col=lane&15, row=(lane>>4)*4+reg ----
  const int cr0 = wm * 128 + ((lane >> 4) << 2);
  const int cc0 = wn * 64 + (lane & 15);
  if (EPI == 0) {
    unsigned short* Co = (unsigned short*)Cv + (long)bz * sC;
#pragma unroll
    for (int mi = 0; mi < 8; mi++)
#pragma unroll
      for (int rr = 0; rr < 4; rr++) {
        long row = m0 + cr0 + mi * 16 + rr;
#pragma unroll
        for (int ni = 0; ni < 4; ni++) {
          long col = n0 + cc0 + ni * 16;
          float v = acc[mi][ni][rr];
          if (bias) v += bias[col];
          Co[row * ldc + col] = f2bf(v);
        }
      }
  } else if (EPI == 1) {
    float* Co = (float*)Cv + (long)bz * sC;
    const int* Mp = mask + (long)bz * sMask;
#pragma unroll
    for (int mi = 0; mi < 8; mi++)
#pragma unroll
      for (int rr = 0; rr < 4; rr++) {
        long row = m0 + cr0 + mi * 16 + rr;
#pragma unroll
        for (int ni = 0; ni < 4; ni++) {
          long col = n0 + cc0 + ni * 16;
          Co[row * ldc + col] = acc[mi][ni][rr] * scale + (float)Mp[row * ldc + col] * -1e9f;
        }
      }
  } else {
    float* Co = (float*)Cv + (long)bz * sC;
#pragma unroll
    for (int mi = 0; mi < 8; mi++)
#pragma unroll
      for (int rr = 0; rr < 4; rr++) {
        long row = m0 + cr0 + mi * 16 + rr;
#pragma unroll
        for (int ni = 0; ni < 4; ni++) {
          long col = n0 + cc0 + ni * 16;
          Co[row * ldc + col] = acc[mi][ni][rr] + bias[col];
        }
      }
  }
}

// ---------- edge gate + softmax, one row per block; writes bf16 attn in place ----------
__global__ __launch_bounds__(256) void k_edge_softmax(float* __restrict__ scores,
                                                      const float* __restrict__ We,
                                                      const float* __restrict__ be) {
  __shared__ float r1[4], r2[4], r3[4];
  const long row = blockIdx.x;
  float* srow = scores + row * (long)NN;
  const int t = threadIdx.x;
  const int lane = t & 63;
  const int w = t >> 6;

  float4 a = *(const float4*)(srow + t * 8);
  float4 b = *(const float4*)(srow + t * 8 + 4);
  float s[8] = {a.x, a.y, a.z, a.w, b.x, b.y, b.z, b.w};
  float4 wa = *(const float4*)(We + t * 8);
  float4 wb = *(const float4*)(We + t * 8 + 4);
  float wv[8] = {wa.x, wa.y, wa.z, wa.w, wb.x, wb.y, wb.z, wb.w};

  float dot = 0.f;
#pragma unroll
  for (int j = 0; j < 8; j++) dot += s[j] * wv[j];
#pragma unroll
  for (int off = 32; off >= 1; off >>= 1) dot += __shfl_down(dot, off);
  if (lane == 0) r1[w] = dot;
  __syncthreads();
  float edot = r1[0] + r1[1] + r1[2] + r1[3] + be[0];
  float edge = 1.0f / (1.0f + expf(-edot));

  float mx = -3.4e38f;
#pragma unroll
  for (int j = 0; j < 8; j++) { s[j] *= edge; mx = fmaxf(mx, s[j]); }
#pragma unroll
  for (int off = 32; off >= 1; off >>= 1) mx = fmaxf(mx, __shfl_down(mx, off));
  if (lane == 0) r2[w] = mx;
  __syncthreads();
  mx = fmaxf(fmaxf(r2[0], r2[1]), fmaxf(r2[2], r2[3]));

  float sum = 0.f;
  float p[8];
#pragma unroll
  for (int j = 0; j < 8; j++) { p[j] = expf(s[j] - mx); sum += p[j]; }
#pragma unroll
  for (int off = 32; off >= 1; off >>= 1) sum += __shfl_down(sum, off);
  if (lane == 0) r3[w] = sum;
  __syncthreads();
  sum = r3[0] + r3[1] + r3[2] + r3[3];
  float inv = 1.0f / sum;

  ushort8 o;
#pragma unroll
  for (int j = 0; j < 8; j++) o[j] = f2bf(p[j] * inv);
  *(ushort8*)((unsigned short*)srow + t * 8) = o;
}

// ---------- launch ----------
extern "C" void kernel_launch(void* const* d_in, const int* in_sizes, int n_in,
                              void* d_out, int out_size, void* d_ws, size_t ws_size,
                              hipStream_t stream) {
  (void)in_sizes; (void)n_in; (void)out_size; (void)ws_size;
  const float* query = (const float*)d_in[0];
  const float* key_  = (const float*)d_in[1];
  const float* value = (const float*)d_in[2];
  const int*   mask  = (const int*)d_in[3];
  const float* Wq = (const float*)d_in[4];
  const float* bq = (const float*)d_in[5];
  const float* Wk = (const float*)d_in[6];
  const float* bk = (const float*)d_in[7];
  const float* Wv = (const float*)d_in[8];
  const float* bv = (const float*)d_in[9];
  const float* We = (const float*)d_in[10];
  const float* be = (const float*)d_in[11];
  const float* Wo = (const float*)d_in[12];
  const float* bo = (const float*)d_in[13];
  float* out = (float*)d_out;

  const long NE = (long)BB * NN * EE;
  const size_t SZ = (size_t)NE * 2;
  char* ws = (char*)d_ws;
  unsigned short* X  = (unsigned short*)(ws);           // conv buffer, later Vt
  unsigned short* Qb = (unsigned short*)(ws + SZ);
  unsigned short* Kb = (unsigned short*)(ws + 2 * SZ);
  unsigned short* Vb = (unsigned short*)(ws + 3 * SZ);  // later O
  unsigned short* Wb = (unsigned short*)(ws + 4 * SZ);  // 4 x E*E bf16
  float* SC = (float*)(ws + 5 * SZ);                    // scores fp32; attn bf16 in place

  const float scale = 1.0f / sqrtf((float)EE);
  dim3 blk(256), blk5(512);
  const long WE2 = (long)EE * EE;

  // weights -> bf16
  k_f32_to_bf16<<<2048, blk, 0, stream>>>(Wq, Wb + 0 * WE2);
  k_f32_to_bf16<<<2048, blk, 0, stream>>>(Wk, Wb + 1 * WE2);
  k_f32_to_bf16<<<2048, blk, 0, stream>>>(Wv, Wb + 2 * WE2);
  k_f32_to_bf16<<<2048, blk, 0, stream>>>(Wo, Wb + 3 * WE2);

  // projections (M = B*N = 8192)
  k_f32_to_bf16<<<8192, blk, 0, stream>>>(query, X);
  k_gemm256<0><<<dim3(8, 32, 1), blk5, 0, stream>>>(X, EE, 0, Wb + 0 * WE2, EE, 0,
      Qb, EE, 0, EE, bq, nullptr, 0, 0.f);
  k_f32_to_bf16<<<8192, blk, 0, stream>>>(key_, X);
  k_gemm256<0><<<dim3(8, 32, 1), blk5, 0, stream>>>(X, EE, 0, Wb + 1 * WE2, EE, 0,
      Kb, EE, 0, EE, bk, nullptr, 0, 0.f);
  k_f32_to_bf16<<<8192, blk, 0, stream>>>(value, X);
  k_gemm256<0><<<dim3(8, 32, 1), blk5, 0, stream>>>(X, EE, 0, Wb + 2 * WE2, EE, 0,
      Vb, EE, 0, EE, bv, nullptr, 0, 0.f);

  // Vt[e,n] = V[n,e]
  k_transpose<<<dim3(32, 32, BB), blk, 0, stream>>>(Vb, X);

  // scores = Q K^T * scale + mask*(-1e9)   [fp32]
  k_gemm256<1><<<dim3(8, 8, BB), blk5, 0, stream>>>(Qb, EE, (long)NN * EE, Kb, EE, (long)NN * EE,
      SC, NN, (long)NN * NN, EE, nullptr, mask, (long)NN * NN, scale);

  // edge gate + softmax -> bf16 attn in place (row stride 2N bf16 elements)
  k_edge_softmax<<<BB * NN, blk, 0, stream>>>(SC, We, be);

  // O = attn * Vt^T  -> Vb region (bf16)
  k_gemm256<0><<<dim3(8, 8, BB), blk5, 0, stream>>>((const unsigned short*)SC, 2 * NN,
      (long)NN * 2 * NN, X, NN, (long)EE * NN, Vb, EE, (long)NN * EE, NN,
      nullptr, nullptr, 0, 0.f);

  // out = O * Wo^T + bo   [fp32]
  k_gemm256<2><<<dim3(8, 32, 1), blk5, 0, stream>>>(Vb, EE, 0, Wb + 3 * WE2, EE, 0,
      out, EE, 0, EE, bo, nullptr, 0, 0.f);
}